// Round 1
// baseline (673.790 us; speedup 1.0000x reference)
//
#include <hip/hip_runtime.h>
#include <hip/hip_bf16.h>

// Problem: L=8 layers; x[L,N,D] f32, centroids[L,K,D] f32; out[L,N,K] f32
//   out = sqrt(max(x2 - 2*x.c + c2, 1e-12))
// N=1024, D=2048, K=4096.
// Strategy: prep pass casts inputs to bf16 in d_ws and computes f32 row norms;
// main kernel is a 128x128-tile bf16 MFMA GEMM (C = A * B^T form, both operands
// read contiguously along D) with fused norm/sqrt epilogue.

#define L_DIM 8
#define N_DIM 1024
#define D_DIM 2048
#define K_DIM 4096

typedef __bf16 bf16x8 __attribute__((ext_vector_type(8)));
typedef float floatx4 __attribute__((ext_vector_type(4)));

// ---------- helpers ----------

__device__ __forceinline__ unsigned short f2bf_rne(float f) {
    unsigned u = __float_as_uint(f);
    unsigned r = (u + 0x7FFFu + ((u >> 16) & 1u)) >> 16;
    return (unsigned short)r;
}

// async global->LDS, 16B per lane. LDS dest = wave-uniform base + lane*16.
__device__ __forceinline__ void lds_cp16(const unsigned short* g, unsigned short* l) {
    __builtin_amdgcn_global_load_lds(
        (const __attribute__((address_space(1))) void*)g,
        (__attribute__((address_space(3))) void*)l,
        16, 0, 0);
}

// ---------- prep: f32 -> bf16 cast + row L2-norm^2 (f32 precision) ----------
// one block (256 thr) per row of length D=2048; 8 elems/thread.
__global__ __launch_bounds__(256) void prep_kernel(const float* __restrict__ src,
                                                   unsigned short* __restrict__ dst,
                                                   float* __restrict__ norms) {
    const int row = blockIdx.x;
    const int t = threadIdx.x;
    const size_t base = (size_t)row * D_DIM + (size_t)t * 8;

    float4 f0 = *(const float4*)(src + base);
    float4 f1 = *(const float4*)(src + base + 4);

    union { unsigned short us[8]; int4 v; } pk;
    pk.us[0] = f2bf_rne(f0.x); pk.us[1] = f2bf_rne(f0.y);
    pk.us[2] = f2bf_rne(f0.z); pk.us[3] = f2bf_rne(f0.w);
    pk.us[4] = f2bf_rne(f1.x); pk.us[5] = f2bf_rne(f1.y);
    pk.us[6] = f2bf_rne(f1.z); pk.us[7] = f2bf_rne(f1.w);
    *(int4*)(dst + base) = pk.v;

    float s = f0.x*f0.x + f0.y*f0.y + f0.z*f0.z + f0.w*f0.w
            + f1.x*f1.x + f1.y*f1.y + f1.z*f1.z + f1.w*f1.w;
    #pragma unroll
    for (int off = 32; off > 0; off >>= 1) s += __shfl_down(s, off, 64);

    __shared__ float red[4];
    if ((t & 63) == 0) red[t >> 6] = s;
    __syncthreads();
    if (t == 0) norms[row] = red[0] + red[1] + red[2] + red[3];
}

// ---------- main MFMA GEMM, 128x128 tile, BK=64, 4 waves ----------
__global__ __launch_bounds__(256) void gemm_mfma(const unsigned short* __restrict__ xb,
                                                 const unsigned short* __restrict__ cb,
                                                 const float* __restrict__ x2,
                                                 const float* __restrict__ c2,
                                                 float* __restrict__ out) {
    __shared__ unsigned short As[128 * 64];   // [row n (128)][d (64)]
    __shared__ unsigned short Bs[128 * 64];   // [centroid k (128)][d (64)]

    const int l  = blockIdx.z;
    const int nb = blockIdx.y;   // 0..7   (N/128)
    const int kb = blockIdx.x;   // 0..31  (K/128)

    const unsigned short* xA = xb + (size_t)l * N_DIM * D_DIM + (size_t)(nb * 128) * D_DIM;
    const unsigned short* cB = cb + (size_t)l * K_DIM * D_DIM + (size_t)(kb * 128) * D_DIM;

    const int t    = threadIdx.x;
    const int wave = t >> 6;           // 0..3 (wave-uniform)
    const int lane = t & 63;
    const int quad = lane >> 4;        // 0..3
    const int lr   = lane & 15;        // 0..15
    const int wr   = (wave >> 1) * 64; // wave row offset in tile
    const int wc   = (wave & 1) * 64;  // wave col offset in tile

    floatx4 acc[4][4];
    const floatx4 zero = {0.f, 0.f, 0.f, 0.f};
    #pragma unroll
    for (int i = 0; i < 4; i++)
        #pragma unroll
        for (int j = 0; j < 4; j++) acc[i][j] = zero;

    for (int d0 = 0; d0 < D_DIM; d0 += 64) {
        // stage 128x64 bf16 tiles: 1024 chunks of 16B each = 256 thr x 4 iters
        #pragma unroll
        for (int i = 0; i < 4; i++) {
            const int id  = i * 256 + t;       // chunk id 0..1023
            const int row = id >> 3;           // 0..127
            const int cc  = id & 7;            // 16B chunk within 64-elem row
            const int ldsbase = (i * 256 + wave * 64) * 8;  // wave-uniform
            lds_cp16(xA + (size_t)row * D_DIM + d0 + cc * 8, &As[ldsbase]);
            lds_cp16(cB + (size_t)row * D_DIM + d0 + cc * 8, &Bs[ldsbase]);
        }
        __syncthreads();   // drains vmcnt (global_load_lds) before barrier

        #pragma unroll
        for (int ks = 0; ks < 2; ks++) {
            bf16x8 a[4], b[4];
            #pragma unroll
            for (int im = 0; im < 4; im++)
                a[im] = *(const bf16x8*)&As[(wr + im * 16 + lr) * 64 + ks * 32 + quad * 8];
            #pragma unroll
            for (int jn = 0; jn < 4; jn++)
                b[jn] = *(const bf16x8*)&Bs[(wc + jn * 16 + lr) * 64 + ks * 32 + quad * 8];
            #pragma unroll
            for (int im = 0; im < 4; im++)
                #pragma unroll
                for (int jn = 0; jn < 4; jn++)
                    acc[im][jn] = __builtin_amdgcn_mfma_f32_16x16x32_bf16(
                        a[im], b[jn], acc[im][jn], 0, 0, 0);
        }
        __syncthreads();
    }

    // epilogue: d2 = x2 - 2*dot + c2 ; out = sqrt(max(d2,1e-12))
    const float* x2l = x2 + l * N_DIM + nb * 128;
    const float* c2l = c2 + l * K_DIM + kb * 128;
    float* outl = out + (size_t)l * N_DIM * K_DIM + (size_t)(nb * 128) * K_DIM + kb * 128;

    #pragma unroll
    for (int im = 0; im < 4; im++) {
        const int rbase = wr + im * 16 + quad * 4;
        #pragma unroll
        for (int jn = 0; jn < 4; jn++) {
            const int col = wc + jn * 16 + lr;
            const float c2v = c2l[col];
            #pragma unroll
            for (int r = 0; r < 4; r++) {
                const int row = rbase + r;
                const float d2 = x2l[row] - 2.0f * acc[im][jn][r] + c2v;
                outl[(size_t)row * K_DIM + col] = sqrtf(fmaxf(d2, 1e-12f));
            }
        }
    }
}

// ---------- fallback (ws too small): self-contained f32, no workspace ----------
__global__ __launch_bounds__(256) void fallback_dist(const float* __restrict__ x,
                                                     const float* __restrict__ c,
                                                     float* __restrict__ out) {
    __shared__ float As[64][33];
    __shared__ float Bs[64][33];
    const int l = blockIdx.z, nb = blockIdx.y, kb = blockIdx.x;
    const float* xA = x + (size_t)l * N_DIM * D_DIM + (size_t)(nb * 64) * D_DIM;
    const float* cB = c + (size_t)l * K_DIM * D_DIM + (size_t)(kb * 64) * D_DIM;
    const int t = threadIdx.x;
    const int tr = t >> 4, tc = t & 15;
    float acc[4][4] = {};
    for (int d0 = 0; d0 < D_DIM; d0 += 32) {
        #pragma unroll
        for (int i = 0; i < 8; i++) {
            const int id = i * 256 + t;
            const int r = id >> 5, cc = id & 31;
            As[r][cc] = xA[(size_t)r * D_DIM + d0 + cc];
            Bs[r][cc] = cB[(size_t)r * D_DIM + d0 + cc];
        }
        __syncthreads();
        #pragma unroll
        for (int kk = 0; kk < 32; kk++) {
            float av[4], bv[4];
            #pragma unroll
            for (int i = 0; i < 4; i++) av[i] = As[tr * 4 + i][kk];
            #pragma unroll
            for (int j = 0; j < 4; j++) bv[j] = Bs[tc * 4 + j][kk];
            #pragma unroll
            for (int i = 0; i < 4; i++)
                #pragma unroll
                for (int j = 0; j < 4; j++) {
                    const float dxy = av[i] - bv[j];
                    acc[i][j] += dxy * dxy;
                }
        }
        __syncthreads();
    }
    float* o = out + (size_t)l * N_DIM * K_DIM + (size_t)(nb * 64) * K_DIM + kb * 64;
    #pragma unroll
    for (int i = 0; i < 4; i++)
        #pragma unroll
        for (int j = 0; j < 4; j++)
            o[(size_t)(tr * 4 + i) * K_DIM + tc * 4 + j] = sqrtf(fmaxf(acc[i][j], 1e-12f));
}

// ---------- launch ----------
extern "C" void kernel_launch(void* const* d_in, const int* in_sizes, int n_in,
                              void* d_out, int out_size, void* d_ws, size_t ws_size,
                              hipStream_t stream) {
    const float* x = (const float*)d_in[0];
    const float* c = (const float*)d_in[1];
    float* out = (float*)d_out;

    constexpr size_t X_ELEMS = (size_t)L_DIM * N_DIM * D_DIM;   // 16.78M
    constexpr size_t C_ELEMS = (size_t)L_DIM * K_DIM * D_DIM;   // 67.1M
    constexpr size_t NEED = X_ELEMS * 2 + C_ELEMS * 2
                          + (size_t)L_DIM * N_DIM * 4 + (size_t)L_DIM * K_DIM * 4;

    if (ws_size >= NEED) {
        unsigned short* xb = (unsigned short*)d_ws;
        unsigned short* cb = xb + X_ELEMS;
        float* x2 = (float*)(cb + C_ELEMS);
        float* c2 = x2 + (size_t)L_DIM * N_DIM;

        prep_kernel<<<L_DIM * N_DIM, 256, 0, stream>>>(x, xb, x2);
        prep_kernel<<<L_DIM * K_DIM, 256, 0, stream>>>(c, cb, c2);
        gemm_mfma<<<dim3(K_DIM / 128, N_DIM / 128, L_DIM), 256, 0, stream>>>(xb, cb, x2, c2, out);
    } else {
        fallback_dist<<<dim3(K_DIM / 64, N_DIM / 64, L_DIM), 256, 0, stream>>>(x, c, out);
    }
}

// Round 2
// 652.571 us; speedup vs baseline: 1.0325x; 1.0325x over previous
//
#include <hip/hip_runtime.h>
#include <hip/hip_bf16.h>

// Problem: L=8 layers; x[L,N,D] f32, centroids[L,K,D] f32; out[L,N,K] f32
//   out = sqrt(max(x2 - 2*x.c + c2, 1e-12))
// N=1024, D=2048, K=4096.
// R1: prep = wave-per-row streaming (was block-per-row, latency-bound at 1.2 TB/s);
//     gemm = XOR-swizzled LDS layout to kill the 8-way ds_read_b128 bank conflicts
//     (5e7 conflict cycles/dispatch = ~30% of kernel time in R0).

#define L_DIM 8
#define N_DIM 1024
#define D_DIM 2048
#define K_DIM 4096

typedef __bf16 bf16x8 __attribute__((ext_vector_type(8)));
typedef float floatx4 __attribute__((ext_vector_type(4)));

// ---------- helpers ----------

__device__ __forceinline__ unsigned short f2bf_rne(float f) {
    unsigned u = __float_as_uint(f);
    unsigned r = (u + 0x7FFFu + ((u >> 16) & 1u)) >> 16;
    return (unsigned short)r;
}

// async global->LDS, 16B per lane. LDS dest = wave-uniform base + lane*16.
__device__ __forceinline__ void lds_cp16(const unsigned short* g, unsigned short* l) {
    __builtin_amdgcn_global_load_lds(
        (const __attribute__((address_space(1))) void*)g,
        (__attribute__((address_space(3))) void*)l,
        16, 0, 0);
}

// ---------- prep: f32 -> bf16 cast + row L2-norm^2 (f32 precision) ----------
// wave-per-row: 4 waves/block, each wave owns one D=2048 row.
// lane handles 8 consecutive floats per pass (2x float4 in, 1x int4 out), 4 passes.
// No LDS, no __syncthreads — pure streaming + shuffle reduce.
__global__ __launch_bounds__(256) void prep_kernel(const float* __restrict__ src,
                                                   unsigned short* __restrict__ dst,
                                                   float* __restrict__ norms) {
    const int wave = threadIdx.x >> 6;
    const int lane = threadIdx.x & 63;
    const int row  = blockIdx.x * 4 + wave;
    const size_t rb = (size_t)row * D_DIM;

    float s = 0.f;
    #pragma unroll
    for (int p = 0; p < 4; p++) {
        const size_t base = rb + (size_t)p * 512 + (size_t)lane * 8;
        float4 f0 = *(const float4*)(src + base);
        float4 f1 = *(const float4*)(src + base + 4);

        union { unsigned short us[8]; int4 v; } pk;
        pk.us[0] = f2bf_rne(f0.x); pk.us[1] = f2bf_rne(f0.y);
        pk.us[2] = f2bf_rne(f0.z); pk.us[3] = f2bf_rne(f0.w);
        pk.us[4] = f2bf_rne(f1.x); pk.us[5] = f2bf_rne(f1.y);
        pk.us[6] = f2bf_rne(f1.z); pk.us[7] = f2bf_rne(f1.w);
        *(int4*)(dst + base) = pk.v;

        s += f0.x*f0.x + f0.y*f0.y + f0.z*f0.z + f0.w*f0.w
           + f1.x*f1.x + f1.y*f1.y + f1.z*f1.z + f1.w*f1.w;
    }
    #pragma unroll
    for (int off = 32; off > 0; off >>= 1) s += __shfl_down(s, off, 64);
    if (lane == 0) norms[row] = s;
}

// ---------- main MFMA GEMM, 128x128 tile, BK=64, 4 waves ----------
// LDS layout XOR-swizzled: LDS[row][cc] holds global chunk (row, cc ^ (row&7)),
// cc = 16B chunk index within the 64-elem row. Staging permutes the global
// source chunk per lane (global_load_lds lane->LDS slot is fixed); fragment
// reads use chunk (c ^ (lr&7)) so 8 consecutive lanes tile all 8 bank groups.
__global__ __launch_bounds__(256) void gemm_mfma(const unsigned short* __restrict__ xb,
                                                 const unsigned short* __restrict__ cb,
                                                 const float* __restrict__ x2,
                                                 const float* __restrict__ c2,
                                                 float* __restrict__ out) {
    __shared__ unsigned short As[128 * 64];   // [row n (128)][d (64)], swizzled
    __shared__ unsigned short Bs[128 * 64];   // [centroid k (128)][d (64)], swizzled

    const int l  = blockIdx.z;
    const int nb = blockIdx.y;   // 0..7   (N/128)
    const int kb = blockIdx.x;   // 0..31  (K/128)

    const unsigned short* xA = xb + (size_t)l * N_DIM * D_DIM + (size_t)(nb * 128) * D_DIM;
    const unsigned short* cB = cb + (size_t)l * K_DIM * D_DIM + (size_t)(kb * 128) * D_DIM;

    const int t    = threadIdx.x;
    const int wave = t >> 6;           // 0..3 (wave-uniform)
    const int lane = t & 63;
    const int quad = lane >> 4;        // 0..3
    const int lr   = lane & 15;        // 0..15
    const int sw   = lr & 7;           // XOR swizzle key for fragment reads
    const int wr   = (wave >> 1) * 64; // wave row offset in tile
    const int wc   = (wave & 1) * 64;  // wave col offset in tile

    floatx4 acc[4][4];
    const floatx4 zero = {0.f, 0.f, 0.f, 0.f};
    #pragma unroll
    for (int i = 0; i < 4; i++)
        #pragma unroll
        for (int j = 0; j < 4; j++) acc[i][j] = zero;

    for (int d0 = 0; d0 < D_DIM; d0 += 64) {
        // stage 128x64 bf16 tiles: 1024 chunks of 16B each = 256 thr x 4 iters
        #pragma unroll
        for (int i = 0; i < 4; i++) {
            const int id  = i * 256 + t;       // LDS chunk id 0..1023
            const int row = id >> 3;           // 0..127
            const int cc  = id & 7;            // LDS 16B chunk within row
            const int gcc = cc ^ (row & 7);    // swizzled global source chunk
            const int ldsbase = (i * 256 + wave * 64) * 8;  // wave-uniform
            lds_cp16(xA + (size_t)row * D_DIM + d0 + gcc * 8, &As[ldsbase]);
            lds_cp16(cB + (size_t)row * D_DIM + d0 + gcc * 8, &Bs[ldsbase]);
        }
        __syncthreads();   // drains vmcnt (global_load_lds) before barrier

        #pragma unroll
        for (int ks = 0; ks < 2; ks++) {
            bf16x8 a[4], b[4];
            #pragma unroll
            for (int im = 0; im < 4; im++)
                a[im] = *(const bf16x8*)&As[(wr + im * 16 + lr) * 64 + ((ks * 4 + quad) ^ sw) * 8];
            #pragma unroll
            for (int jn = 0; jn < 4; jn++)
                b[jn] = *(const bf16x8*)&Bs[(wc + jn * 16 + lr) * 64 + ((ks * 4 + quad) ^ sw) * 8];
            #pragma unroll
            for (int im = 0; im < 4; im++)
                #pragma unroll
                for (int jn = 0; jn < 4; jn++)
                    acc[im][jn] = __builtin_amdgcn_mfma_f32_16x16x32_bf16(
                        a[im], b[jn], acc[im][jn], 0, 0, 0);
        }
        __syncthreads();
    }

    // epilogue: d2 = x2 - 2*dot + c2 ; out = sqrt(max(d2,1e-12))
    const float* x2l = x2 + l * N_DIM + nb * 128;
    const float* c2l = c2 + l * K_DIM + kb * 128;
    float* outl = out + (size_t)l * N_DIM * K_DIM + (size_t)(nb * 128) * K_DIM + kb * 128;

    #pragma unroll
    for (int im = 0; im < 4; im++) {
        const int rbase = wr + im * 16 + quad * 4;
        #pragma unroll
        for (int jn = 0; jn < 4; jn++) {
            const int col = wc + jn * 16 + lr;
            const float c2v = c2l[col];
            #pragma unroll
            for (int r = 0; r < 4; r++) {
                const int row = rbase + r;
                const float d2 = x2l[row] - 2.0f * acc[im][jn][r] + c2v;
                outl[(size_t)row * K_DIM + col] = sqrtf(fmaxf(d2, 1e-12f));
            }
        }
    }
}

// ---------- fallback (ws too small): self-contained f32, no workspace ----------
__global__ __launch_bounds__(256) void fallback_dist(const float* __restrict__ x,
                                                     const float* __restrict__ c,
                                                     float* __restrict__ out) {
    __shared__ float As[64][33];
    __shared__ float Bs[64][33];
    const int l = blockIdx.z, nb = blockIdx.y, kb = blockIdx.x;
    const float* xA = x + (size_t)l * N_DIM * D_DIM + (size_t)(nb * 64) * D_DIM;
    const float* cB = c + (size_t)l * K_DIM * D_DIM + (size_t)(kb * 64) * D_DIM;
    const int t = threadIdx.x;
    const int tr = t >> 4, tc = t & 15;
    float acc[4][4] = {};
    for (int d0 = 0; d0 < D_DIM; d0 += 32) {
        #pragma unroll
        for (int i = 0; i < 8; i++) {
            const int id = i * 256 + t;
            const int r = id >> 5, cc = id & 31;
            As[r][cc] = xA[(size_t)r * D_DIM + d0 + cc];
            Bs[r][cc] = cB[(size_t)r * D_DIM + d0 + cc];
        }
        __syncthreads();
        #pragma unroll
        for (int kk = 0; kk < 32; kk++) {
            float av[4], bv[4];
            #pragma unroll
            for (int i = 0; i < 4; i++) av[i] = As[tr * 4 + i][kk];
            #pragma unroll
            for (int j = 0; j < 4; j++) bv[j] = Bs[tc * 4 + j][kk];
            #pragma unroll
            for (int i = 0; i < 4; i++)
                #pragma unroll
                for (int j = 0; j < 4; j++) {
                    const float dxy = av[i] - bv[j];
                    acc[i][j] += dxy * dxy;
                }
        }
        __syncthreads();
    }
    float* o = out + (size_t)l * N_DIM * K_DIM + (size_t)(nb * 64) * K_DIM + kb * 64;
    #pragma unroll
    for (int i = 0; i < 4; i++)
        #pragma unroll
        for (int j = 0; j < 4; j++)
            o[(size_t)(tr * 4 + i) * K_DIM + tc * 4 + j] = sqrtf(fmaxf(acc[i][j], 1e-12f));
}

// ---------- launch ----------
extern "C" void kernel_launch(void* const* d_in, const int* in_sizes, int n_in,
                              void* d_out, int out_size, void* d_ws, size_t ws_size,
                              hipStream_t stream) {
    const float* x = (const float*)d_in[0];
    const float* c = (const float*)d_in[1];
    float* out = (float*)d_out;

    constexpr size_t X_ELEMS = (size_t)L_DIM * N_DIM * D_DIM;   // 16.78M
    constexpr size_t C_ELEMS = (size_t)L_DIM * K_DIM * D_DIM;   // 67.1M
    constexpr size_t NEED = X_ELEMS * 2 + C_ELEMS * 2
                          + (size_t)L_DIM * N_DIM * 4 + (size_t)L_DIM * K_DIM * 4;

    if (ws_size >= NEED) {
        unsigned short* xb = (unsigned short*)d_ws;
        unsigned short* cb = xb + X_ELEMS;
        float* x2 = (float*)(cb + C_ELEMS);
        float* c2 = x2 + (size_t)L_DIM * N_DIM;

        prep_kernel<<<L_DIM * N_DIM / 4, 256, 0, stream>>>(x, xb, x2);
        prep_kernel<<<L_DIM * K_DIM / 4, 256, 0, stream>>>(c, cb, c2);
        gemm_mfma<<<dim3(K_DIM / 128, N_DIM / 128, L_DIM), 256, 0, stream>>>(xb, cb, x2, c2, out);
    } else {
        fallback_dist<<<dim3(K_DIM / 64, N_DIM / 64, L_DIM), 256, 0, stream>>>(x, c, out);
    }
}

// Round 3
// 636.399 us; speedup vs baseline: 1.0588x; 1.0254x over previous
//
#include <hip/hip_runtime.h>
#include <hip/hip_bf16.h>

// Problem: L=8 layers; x[L,N,D] f32, centroids[L,K,D] f32; out[L,N,K] f32
//   out = sqrt(max(x2 - 2*x.c + c2, 1e-12))
// N=1024, D=2048, K=4096.
// R2 evidence: swizzle killed all LDS bank conflicts (5e7 -> 0) but gemm only
// 270->240us: issue-side cost per MFMA too high (32 MFMA + 16 ds_read + 8 glds
// per iter at 16x16x32). R3: switch to 32x32x16 MFMA (half the MFMA instrs,
// higher pipe ceiling 2382 vs 2075 TF, half the a/b frag regs), hoist staging
// pointers, fuse prep into one launch. The ~410us residual (total - gemm) is
// invariant across prep rewrites -> fixed harness memops, not optimizable here.

#define L_DIM 8
#define N_DIM 1024
#define D_DIM 2048
#define K_DIM 4096

typedef __bf16 bf16x8 __attribute__((ext_vector_type(8)));
typedef float floatx16 __attribute__((ext_vector_type(16)));

// ---------- helpers ----------

__device__ __forceinline__ unsigned short f2bf_rne(float f) {
    unsigned u = __float_as_uint(f);
    unsigned r = (u + 0x7FFFu + ((u >> 16) & 1u)) >> 16;
    return (unsigned short)r;
}

// async global->LDS, 16B per lane. LDS dest = wave-uniform base + lane*16.
__device__ __forceinline__ void lds_cp16(const unsigned short* g, unsigned short* l) {
    __builtin_amdgcn_global_load_lds(
        (const __attribute__((address_space(1))) void*)g,
        (__attribute__((address_space(3))) void*)l,
        16, 0, 0);
}

// ---------- prep: f32 -> bf16 cast + row L2-norm^2 (f32 precision) ----------
// One launch for x and c. Wave-per-row; 4 rows/block; pure streaming +
// shuffle reduce (no LDS, no barriers).
__global__ __launch_bounds__(256) void prep_all(const float* __restrict__ x,
                                                const float* __restrict__ c,
                                                unsigned short* __restrict__ xb,
                                                unsigned short* __restrict__ cb,
                                                float* __restrict__ x2,
                                                float* __restrict__ c2) {
    const int wave = threadIdx.x >> 6;
    const int lane = threadIdx.x & 63;
    const int gw   = blockIdx.x * 4 + wave;   // 0 .. L*(N+K)-1, wave-uniform

    const float* src; unsigned short* dst; float* nrm; int row;
    if (gw < L_DIM * N_DIM) { src = x; dst = xb; nrm = x2; row = gw; }
    else { src = c; dst = cb; nrm = c2; row = gw - L_DIM * N_DIM; }

    const size_t rb = (size_t)row * D_DIM;
    float s = 0.f;
    #pragma unroll
    for (int p = 0; p < 4; p++) {
        const size_t base = rb + (size_t)p * 512 + (size_t)lane * 8;
        float4 f0 = *(const float4*)(src + base);
        float4 f1 = *(const float4*)(src + base + 4);

        union { unsigned short us[8]; int4 v; } pk;
        pk.us[0] = f2bf_rne(f0.x); pk.us[1] = f2bf_rne(f0.y);
        pk.us[2] = f2bf_rne(f0.z); pk.us[3] = f2bf_rne(f0.w);
        pk.us[4] = f2bf_rne(f1.x); pk.us[5] = f2bf_rne(f1.y);
        pk.us[6] = f2bf_rne(f1.z); pk.us[7] = f2bf_rne(f1.w);
        *(int4*)(dst + base) = pk.v;

        s += f0.x*f0.x + f0.y*f0.y + f0.z*f0.z + f0.w*f0.w
           + f1.x*f1.x + f1.y*f1.y + f1.z*f1.z + f1.w*f1.w;
    }
    #pragma unroll
    for (int off = 32; off > 0; off >>= 1) s += __shfl_down(s, off, 64);
    if (lane == 0) nrm[row] = s;
}

// ---------- main MFMA GEMM: 128x128 tile, BK=64, 4 waves, 32x32x16 bf16 ----------
// LDS XOR-swizzled: LDS[row][cc] holds global chunk (row, cc ^ (row&7)),
// cc = 16B chunk within the 64-elem row. Fragment reads use chunk
// (c ^ (lane&7)) -> conflict-free (verified R2: SQ_LDS_BANK_CONFLICT = 0).
// Per wave: 2x2 microtiles of 32x32. A/B frag: m = lane&31, k = (lane>>5)*8+j.
// C/D frag (HW-verified m74/m101): col = lane&31, row = (reg&3)+8*(reg>>2)+4*(lane>>5).
__global__ __launch_bounds__(256) void gemm_mfma(const unsigned short* __restrict__ xb,
                                                 const unsigned short* __restrict__ cb,
                                                 const float* __restrict__ x2,
                                                 const float* __restrict__ c2,
                                                 float* __restrict__ out) {
    __shared__ unsigned short As[128 * 64];   // [row n (128)][d (64)], swizzled
    __shared__ unsigned short Bs[128 * 64];   // [centroid k (128)][d (64)], swizzled

    const int l  = blockIdx.z;
    const int nb = blockIdx.y;   // 0..7   (N/128)
    const int kb = blockIdx.x;   // 0..31  (K/128)

    const unsigned short* xA = xb + (size_t)l * N_DIM * D_DIM + (size_t)(nb * 128) * D_DIM;
    const unsigned short* cB = cb + (size_t)l * K_DIM * D_DIM + (size_t)(kb * 128) * D_DIM;

    const int t    = threadIdx.x;
    const int wave = t >> 6;           // 0..3 (wave-uniform)
    const int lane = t & 63;
    const int l31  = lane & 31;
    const int lh   = lane >> 5;        // 0..1
    const int swz  = lane & 7;         // XOR swizzle key for fragment reads
    const int wr   = (wave >> 1) * 64; // wave row offset in tile
    const int wc   = (wave & 1) * 64;  // wave col offset in tile

    // staging: per-thread hoisted global pointers (advance by 64 each iter)
    const unsigned short* pA[4];
    const unsigned short* pB[4];
    unsigned short* ldsA[4];
    unsigned short* ldsB[4];
    #pragma unroll
    for (int i = 0; i < 4; i++) {
        const int id  = i * 256 + t;       // LDS chunk id 0..1023
        const int row = id >> 3;           // 0..127
        const int cc  = id & 7;            // LDS 16B chunk within row
        const int gcc = cc ^ (row & 7);    // swizzled global source chunk
        pA[i] = xA + (size_t)row * D_DIM + gcc * 8;
        pB[i] = cB + (size_t)row * D_DIM + gcc * 8;
        ldsA[i] = &As[(i * 256 + wave * 64) * 8];   // wave-uniform
        ldsB[i] = &Bs[(i * 256 + wave * 64) * 8];
    }

    floatx16 acc[2][2] = {};

    for (int d0 = 0; d0 < D_DIM; d0 += 64) {
        #pragma unroll
        for (int i = 0; i < 4; i++) {
            lds_cp16(pA[i], ldsA[i]);
            lds_cp16(pB[i], ldsB[i]);
            pA[i] += 64; pB[i] += 64;
        }
        __syncthreads();   // drains vmcnt (global_load_lds) before barrier

        #pragma unroll
        for (int s = 0; s < 4; s++) {      // 4 k16-steps of BK=64
            const int co = (((s << 1) | lh) ^ swz) << 3;   // swizzled 16B chunk -> elem offset
            bf16x8 a[2], b[2];
            a[0] = *(const bf16x8*)&As[(wr +      l31) * 64 + co];
            a[1] = *(const bf16x8*)&As[(wr + 32 + l31) * 64 + co];
            b[0] = *(const bf16x8*)&Bs[(wc +      l31) * 64 + co];
            b[1] = *(const bf16x8*)&Bs[(wc + 32 + l31) * 64 + co];
            #pragma unroll
            for (int i = 0; i < 2; i++)
                #pragma unroll
                for (int j = 0; j < 2; j++)
                    acc[i][j] = __builtin_amdgcn_mfma_f32_32x32x16_bf16(
                        a[i], b[j], acc[i][j], 0, 0, 0);
        }
        __syncthreads();
    }

    // epilogue: d2 = x2 - 2*dot + c2 ; out = sqrt(max(d2,1e-12))
    const float* x2l = x2 + l * N_DIM + nb * 128;
    const float* c2l = c2 + l * K_DIM + kb * 128;
    float* outl = out + (size_t)l * N_DIM * K_DIM + (size_t)(nb * 128) * K_DIM + kb * 128;

    #pragma unroll
    for (int i = 0; i < 2; i++) {
        #pragma unroll
        for (int j = 0; j < 2; j++) {
            const int col = wc + j * 32 + l31;
            const float c2v = c2l[col];
            #pragma unroll
            for (int r = 0; r < 16; r++) {
                const int row = wr + i * 32 + (r & 3) + 8 * (r >> 2) + 4 * lh;
                const float d2 = x2l[row] - 2.0f * acc[i][j][r] + c2v;
                outl[(size_t)row * K_DIM + col] = sqrtf(fmaxf(d2, 1e-12f));
            }
        }
    }
}

// ---------- fallback (ws too small): self-contained f32, no workspace ----------
__global__ __launch_bounds__(256) void fallback_dist(const float* __restrict__ x,
                                                     const float* __restrict__ c,
                                                     float* __restrict__ out) {
    __shared__ float As[64][33];
    __shared__ float Bs[64][33];
    const int l = blockIdx.z, nb = blockIdx.y, kb = blockIdx.x;
    const float* xA = x + (size_t)l * N_DIM * D_DIM + (size_t)(nb * 64) * D_DIM;
    const float* cB = c + (size_t)l * K_DIM * D_DIM + (size_t)(kb * 64) * D_DIM;
    const int t = threadIdx.x;
    const int tr = t >> 4, tc = t & 15;
    float acc[4][4] = {};
    for (int d0 = 0; d0 < D_DIM; d0 += 32) {
        #pragma unroll
        for (int i = 0; i < 8; i++) {
            const int id = i * 256 + t;
            const int r = id >> 5, cc = id & 31;
            As[r][cc] = xA[(size_t)r * D_DIM + d0 + cc];
            Bs[r][cc] = cB[(size_t)r * D_DIM + d0 + cc];
        }
        __syncthreads();
        #pragma unroll
        for (int kk = 0; kk < 32; kk++) {
            float av[4], bv[4];
            #pragma unroll
            for (int i = 0; i < 4; i++) av[i] = As[tr * 4 + i][kk];
            #pragma unroll
            for (int j = 0; j < 4; j++) bv[j] = Bs[tc * 4 + j][kk];
            #pragma unroll
            for (int i = 0; i < 4; i++)
                #pragma unroll
                for (int j = 0; j < 4; j++) {
                    const float dxy = av[i] - bv[j];
                    acc[i][j] += dxy * dxy;
                }
        }
        __syncthreads();
    }
    float* o = out + (size_t)l * N_DIM * K_DIM + (size_t)(nb * 64) * K_DIM + kb * 64;
    #pragma unroll
    for (int i = 0; i < 4; i++)
        #pragma unroll
        for (int j = 0; j < 4; j++)
            o[(size_t)(tr * 4 + i) * K_DIM + tc * 4 + j] = sqrtf(fmaxf(acc[i][j], 1e-12f));
}

// ---------- launch ----------
extern "C" void kernel_launch(void* const* d_in, const int* in_sizes, int n_in,
                              void* d_out, int out_size, void* d_ws, size_t ws_size,
                              hipStream_t stream) {
    const float* x = (const float*)d_in[0];
    const float* c = (const float*)d_in[1];
    float* out = (float*)d_out;

    constexpr size_t X_ELEMS = (size_t)L_DIM * N_DIM * D_DIM;   // 16.78M
    constexpr size_t C_ELEMS = (size_t)L_DIM * K_DIM * D_DIM;   // 67.1M
    constexpr size_t NEED = X_ELEMS * 2 + C_ELEMS * 2
                          + (size_t)L_DIM * N_DIM * 4 + (size_t)L_DIM * K_DIM * 4;

    if (ws_size >= NEED) {
        unsigned short* xb = (unsigned short*)d_ws;
        unsigned short* cb = xb + X_ELEMS;
        float* x2 = (float*)(cb + C_ELEMS);
        float* c2 = x2 + (size_t)L_DIM * N_DIM;

        prep_all<<<L_DIM * (N_DIM + K_DIM) / 4, 256, 0, stream>>>(x, c, xb, cb, x2, c2);
        gemm_mfma<<<dim3(K_DIM / 128, N_DIM / 128, L_DIM), 256, 0, stream>>>(xb, cb, x2, c2, out);
    } else {
        fallback_dist<<<dim3(K_DIM / 64, N_DIM / 64, L_DIM), 256, 0, stream>>>(x, c, out);
    }
}